// Round 6
// baseline (73.616 us; speedup 1.0000x reference)
//
#include <hip/hip_runtime.h>

#define B_ 32
#define N_ 256
#define C_ 512
#define O_ 512
#define S_ 512

#define WST 520   // wt row stride in shorts: 1040 B, 16B-aligned, bank-shift 4/row

typedef __attribute__((ext_vector_type(8))) short short8;
typedef __attribute__((ext_vector_type(4))) float f32x4;

__device__ __forceinline__ short f2bf(float f) {
    union { float f; unsigned u; } v; v.f = f;
    unsigned r = v.u + 0x7fffu + ((v.u >> 16) & 1u);  // RNE (inputs finite)
    return (short)(r >> 16);
}
__device__ __forceinline__ float bf2f(short s) {
    union { unsigned u; float f; } v; v.u = ((unsigned)(unsigned short)s) << 16;
    return v.f;
}

// o-chunked schedule: block = (n, 128-row o-panel); 8 chunks of 16 o-rows x full K.
// Weight is read strictly sequentially (each DRAM page touched once).
// Waves: wv = (kh<<1)|mb ; mb = b-half (m-frag), kh = K-half. 2-way K reduction in LDS.
__global__ __launch_bounds__(256, 4) void tml_kernel(const float* __restrict__ x,
                                                     const float* __restrict__ s,
                                                     const float* __restrict__ weight,
                                                     const float* __restrict__ bias,
                                                     const float* __restrict__ s_w,
                                                     const float* __restrict__ s_b,
                                                     float* __restrict__ out) {
    // XCD-aware bijective remap (nwg=1024 divisible by 8)
    const int h       = blockIdx.x;
    const int logical = (h & 7) * 128 + (h >> 3);
    const int n       = logical >> 2;
    const int ot      = logical & 3;

    const int tid  = threadIdx.x;
    const int wv   = tid >> 6;
    const int mb   = wv & 1;      // which 16-row b half
    const int kh   = wv >> 1;     // which 256-wide K half
    const int lane = tid & 63;
    const int l16  = lane & 15;
    const int lk   = lane >> 4;

    __shared__ short wt[16][WST];     // current weight chunk, bf16 (16.6 KB)
    __shared__ f32x4 redv[2][64];     // K-split partial accs  (2 KB)
    __shared__ float reds[2][64];     // K-split partial ssq   (0.5 KB)
    __shared__ float sm_lds[B_];

    const float* wpanel = weight + (size_t)n * (O_ * C_) + (size_t)(ot * 128) * C_;

    // ---- issue chunk-0 loads first; latency hides under smap + A-frag prologue
    float4 rg[8];
#pragma unroll
    for (int i = 0; i < 8; ++i)
        rg[i] = *(const float4*)(wpanel + (size_t)(i * 256 + tid) * 4);

    // ---- fused smap: sm_lds[b] = gain * dot(s[b,:], s_w[n,:]) + s_b[n]
    {
        const int b    = tid >> 3;
        const int slot = tid & 7;
        const float* sp = s   + (size_t)b * S_ + slot * 64;
        const float* wp = s_w + (size_t)n * S_ + slot * 64;
        float sum = 0.f;
#pragma unroll
        for (int j = 0; j < 16; ++j) {
            float4 sv  = *(const float4*)(sp + 4 * j);
            float4 wv4 = *(const float4*)(wp + 4 * j);
            sum += sv.x * wv4.x + sv.y * wv4.y + sv.z * wv4.z + sv.w * wv4.w;
        }
        sum += __shfl_xor(sum, 1, 64);
        sum += __shfl_xor(sum, 2, 64);
        sum += __shfl_xor(sum, 4, 64);
        if (slot == 0) sm_lds[b] = sum * 0.04419417382415922f + s_b[n];
    }

    // ---- A-fragments in registers for the whole kernel: this wave's 16 b-rows x its K-half
    short8 afr[8];
    {
        const float* xb = x + ((size_t)(mb * 16 + l16) * N_ + n) * C_ + kh * 256 + lk * 8;
#pragma unroll
        for (int ks = 0; ks < 8; ++ks) {
            float4 u = *(const float4*)(xb + ks * 32);
            float4 w = *(const float4*)(xb + ks * 32 + 4);
            short8 a;
            a[0] = f2bf(u.x); a[1] = f2bf(u.y); a[2] = f2bf(u.z); a[3] = f2bf(u.w);
            a[4] = f2bf(w.x); a[5] = f2bf(w.y); a[6] = f2bf(w.z); a[7] = f2bf(w.w);
            afr[ks] = a;
        }
    }

    // ---- commit chunk 0 to LDS (row = f4/128 since a row is 128 float4)
#pragma unroll
    for (int i = 0; i < 8; ++i) {
        int f4 = i * 256 + tid;
        int row = f4 >> 7, c4 = (f4 & 127) << 2;
        short4 hv;
        hv.x = f2bf(rg[i].x); hv.y = f2bf(rg[i].y); hv.z = f2bf(rg[i].z); hv.w = f2bf(rg[i].w);
        *(short4*)&wt[row][c4] = hv;
    }
    __syncthreads();

    for (int c = 0; c < 8; ++c) {
        // A: issue next chunk's sequential loads (in flight across both barriers)
        if (c + 1 < 8) {
#pragma unroll
            for (int i = 0; i < 8; ++i)
                rg[i] = *(const float4*)(wpanel + (size_t)(c + 1) * 8192
                                         + (size_t)(i * 256 + tid) * 4);
        }

        // B: MFMA over this wave's K-half + ssq from the bf16 B-frags
        f32x4 acc = {0.f, 0.f, 0.f, 0.f};
        float ssq = 0.f;
#pragma unroll
        for (int ks = 0; ks < 8; ++ks) {
            short8 bf = *(const short8*)&wt[l16][kh * 256 + ks * 32 + lk * 8];
#pragma unroll
            for (int j = 0; j < 8; ++j) { float fv = bf2f(bf[j]); ssq += fv * fv; }
            acc = __builtin_amdgcn_mfma_f32_16x16x32_bf16(afr[ks], bf, acc, 0, 0, 0);
        }
        // fold lk-quarters of ssq (per o=l16): every lane ends with its half-K ssq
        ssq += __shfl_xor(ssq, 16, 64);
        ssq += __shfl_xor(ssq, 32, 64);

        // C: kh=1 waves publish partials
        if (kh) { redv[mb][lane] = acc; reds[mb][lane] = ssq; }
        __syncthreads();   // bar1: red published; wt free to overwrite

        // D: stage chunk+1 into wt (all waves) + reduce/epilogue (kh=0 waves)
        if (c + 1 < 8) {
#pragma unroll
            for (int i = 0; i < 8; ++i) {
                int f4 = i * 256 + tid;
                int row = f4 >> 7, c4 = (f4 & 127) << 2;
                short4 hv;
                hv.x = f2bf(rg[i].x); hv.y = f2bf(rg[i].y);
                hv.z = f2bf(rg[i].z); hv.w = f2bf(rg[i].w);
                *(short4*)&wt[row][c4] = hv;
            }
        }
        if (!kh) {
            const f32x4 pacc = redv[mb][lane];
            const float sq   = ssq + reds[mb][lane];
            const int obase  = ot * 128 + c * 16;
            const float bv   = bias[n * O_ + obase + l16];
#pragma unroll
            for (int r = 0; r < 4; ++r) {
                const int b     = mb * 16 + lk * 4 + r;
                const float smv = sm_lds[b];
                const float dec = rsqrtf(smv * smv * sq + 1e-8f);
                out[(size_t)b * (N_ * O_) + n * O_ + obase + l16] =
                    (acc[r] + pacc[r]) * smv * dec + bv;
            }
        }
        if (c + 1 < 8) __syncthreads();   // bar2: wt ready for next MFMA
    }
}

extern "C" void kernel_launch(void* const* d_in, const int* in_sizes, int n_in,
                              void* d_out, int out_size, void* d_ws, size_t ws_size,
                              hipStream_t stream) {
    const float* x      = (const float*)d_in[0];
    const float* s      = (const float*)d_in[1];
    const float* weight = (const float*)d_in[2];
    const float* bias   = (const float*)d_in[3];
    const float* s_w    = (const float*)d_in[4];
    const float* s_b    = (const float*)d_in[5];
    float* out = (float*)d_out;

    tml_kernel<<<N_ * 4, 256, 0, stream>>>(x, s, weight, bias, s_w, s_b, out);
}